// Round 2
// baseline (429.738 us; speedup 1.0000x reference)
//
#include <hip/hip_runtime.h>
#include <math.h>

typedef _Float16 f16;
typedef __attribute__((ext_vector_type(4))) _Float16 f16x4;
typedef __attribute__((ext_vector_type(8))) _Float16 f16x8;
typedef __attribute__((ext_vector_type(4))) float f32x4;

#define B_    4
#define L_    1024
#define H_    768
#define NH_   12
#define NE_   42
#define M_    8
#define E2_   1536              // 2*H
#define HTP_  1792              // HT rows padded to 28*64
#define OUT_HALF 5419008LL      // B*NE*NE*H

// ---------------- ent_emb: masked logsumexp over mentions -> f16 [168][768]
__global__ void k_ent_emb(const float* __restrict__ seq,
                          const int* __restrict__ mpos,
                          const int* __restrict__ mmask,
                          f16* __restrict__ ent) {
    int e = blockIdx.x, b = blockIdx.y;
    int tid = threadIdx.x;
    const int* mp = mpos  + (b*NE_ + e)*M_;
    const int* mk = mmask + (b*NE_ + e)*M_;
    int pos[M_], msk[M_];
#pragma unroll
    for (int m = 0; m < M_; m++) { msk[m] = mk[m]; pos[m] = mp[m] + 1; }
#pragma unroll
    for (int q = 0; q < 3; q++) {
        int h = tid + q*256;
        float mx = -1e30f, vals[M_];
#pragma unroll
        for (int m = 0; m < M_; m++) {
            vals[m] = 0.f;
            if (msk[m]) {
                float v = seq[((long long)b*L_ + pos[m])*H_ + h];
                vals[m] = v; mx = fmaxf(mx, v);
            }
        }
        float s = 0.f;
#pragma unroll
        for (int m = 0; m < M_; m++) if (msk[m]) s += expf(vals[m] - mx);
        float lse = (mx > -1e29f) ? mx + logf(s) : 0.f;
        ent[(b*NE_ + e)*H_ + h] = (f16)lse;
    }
}

// ---------------- ent_att: mean over valid mentions -> f32 [B][NE][NH][L]
__global__ void k_ent_att(const float* __restrict__ attn,
                          const int* __restrict__ mpos,
                          const int* __restrict__ mmask,
                          float* __restrict__ eatt) {
    int nh = blockIdx.x, e = blockIdx.y, b = blockIdx.z;
    int tid = threadIdx.x;
    int l0 = tid * 4;
    const int* mp = mpos  + (b*NE_ + e)*M_;
    const int* mk = mmask + (b*NE_ + e)*M_;
    const float* abase = attn + (long long)(b*NH_ + nh) * L_ * L_;
    f32x4 acc = {0,0,0,0}; int cnt = 0;
#pragma unroll
    for (int m = 0; m < M_; m++) {
        if (mk[m]) {                       // wave-uniform branch
            cnt++;
            const float* row = abase + (long long)(mp[m] + 1) * L_;
            acc += *(const f32x4*)(row + l0);
        }
    }
    float inv = 1.f / (float)(cnt > 0 ? cnt : 1);
    acc *= inv;
    *(f32x4*)(eatt + ((long long)(b*NE_ + e)*NH_ + nh)*L_ + l0) = acc;
}

// ---------------- ht: (1/NH) sum_h ea_i*ea_j, relu, L-normalize -> f16 HT [B][HTP][L]
__global__ void k_ht(const float* __restrict__ eatt, f16* __restrict__ HT) {
    int j = blockIdx.x, i = blockIdx.y, b = blockIdx.z;
    int tid = threadIdx.x;
    int l0 = tid * 4;
    const float* ei = eatt + (long long)(b*NE_ + i)*NH_*L_;
    const float* ej = eatt + (long long)(b*NE_ + j)*NH_*L_;
    f32x4 acc = {0,0,0,0};
#pragma unroll
    for (int h = 0; h < NH_; h++) {
        f32x4 vi = *(const f32x4*)(ei + h*L_ + l0);
        f32x4 vj = *(const f32x4*)(ej + h*L_ + l0);
        acc += vi * vj;
    }
    float v[4]; float s = 0.f;
#pragma unroll
    for (int r = 0; r < 4; r++) {
        float t = acc[r] * (1.f/12.f);
        t = t > 0.f ? t : 0.f;
        v[r] = t; s += t;
    }
    int wave = tid >> 6, lane = tid & 63;
#pragma unroll
    for (int m = 1; m < 64; m <<= 1) s += __shfl_xor(s, m, 64);
    __shared__ float red[4];
    if (lane == 0) red[wave] = s;
    __syncthreads();
    float S = red[0] + red[1] + red[2] + red[3];
    float sc = 1.f / (S + 1e-10f);
    f16x4 o = {(f16)(v[0]*sc), (f16)(v[1]*sc), (f16)(v[2]*sc), (f16)(v[3]*sc)};
    *(f16x4*)(HT + ((long long)b*HTP_ + i*NE_ + j)*L_ + l0) = o;
}

// ---------------- prep: transposed concat weights [c][h] (f16) + bias concat (f32)
__global__ void k_prep(const float* __restrict__ Wh, const float* __restrict__ bh,
                       const float* __restrict__ Wt, const float* __restrict__ bt,
                       f16* __restrict__ wtop, f16* __restrict__ wbot,
                       float* __restrict__ bcat) {
    int idx = blockIdx.x*256 + threadIdx.x;
    if (idx < E2_*H_) {
        int c = idx / H_;
        int h = idx - c*H_;
        float tp, bo;
        if (c < H_) { tp = Wh[h*H_ + c];          bo = Wh[(H_ + h)*H_ + c]; }
        else        { tp = Wt[h*H_ + (c - H_)];   bo = Wt[(H_ + h)*H_ + (c - H_)]; }
        wtop[idx] = (f16)tp; wbot[idx] = (f16)bo;
    }
    if (idx < E2_) bcat[idx] = (idx < H_) ? bh[idx] : bt[idx - H_];
}

// ---------------- seq f32 -> f16 copy
__global__ void k_seq16(const float* __restrict__ seq, f16* __restrict__ seq16) {
    int idx = (blockIdx.x*256 + threadIdx.x) * 4;
    f32x4 v = *(const f32x4*)(seq + idx);
    f16x4 o = {(f16)v[0], (f16)v[1], (f16)v[2], (f16)v[3]};
    *(f16x4*)(seq16 + idx) = o;
}

// ---------------- MFMA f16 GEMM, 64x64 tile, BK=32, B pre-transposed [N][K]
// MODE 0: het = A@B^T + bcat (f32 out)
// MODE 1: store C transposed as f16 (seqWT[c][l])
// MODE 2: tanh(C + het-bias), split-write to d_out halves (f32)
#define BM 64
#define BN 64
#define BK 32
#define LDSS 40   // LDS row stride (elems); 80 B/row keeps 16B alignment, breaks bank aliasing

template<int MODE>
__global__ __launch_bounds__(256)
void k_gemm(const f16* __restrict__ A, const f16* __restrict__ BT,
            int M, int K, long long strideA, long long strideBT,
            float* __restrict__ het, const float* __restrict__ bcat,
            float* __restrict__ outp, f16* __restrict__ outp16) {
    __shared__ __align__(16) f16 As[BM*LDSS];
    __shared__ __align__(16) f16 Bs[BN*LDSS];
    int bm = blockIdx.x*BM, bn = blockIdx.y*BN, bz = blockIdx.z;
    const f16* Ab = A + strideA*bz;
    const f16* Bb = BT + strideBT*bz;
    int tid = threadIdx.x;
    int wave = tid >> 6, lane = tid & 63;
    int wm = (wave >> 1)*32, wn = (wave & 1)*32;
    int lo4 = lane & 15, kq = (lane >> 4)*8;
    int srow = tid >> 2, scol = (tid & 3)*8;
    bool aval = (bm + srow) < M;             // M-guard (HT pad rows, het M=168)
    const f16* aptr = Ab + (long long)(bm + srow)*K + scol;
    const f16* bptr = Bb + (long long)(bn + srow)*K + scol;
    f32x4 acc[2][2] = {};
    for (int k0 = 0; k0 < K; k0 += BK) {
        uint4 zero = {0,0,0,0};
        uint4 av = aval ? *(const uint4*)(aptr + k0) : zero;
        uint4 bv = *(const uint4*)(bptr + k0);
        __syncthreads();
        *(uint4*)(As + srow*LDSS + scol) = av;
        *(uint4*)(Bs + srow*LDSS + scol) = bv;
        __syncthreads();
        f16x8 a0 = *(const f16x8*)(As + (wm +      lo4)*LDSS + kq);
        f16x8 a1 = *(const f16x8*)(As + (wm + 16 + lo4)*LDSS + kq);
        f16x8 b0 = *(const f16x8*)(Bs + (wn +      lo4)*LDSS + kq);
        f16x8 b1 = *(const f16x8*)(Bs + (wn + 16 + lo4)*LDSS + kq);
        acc[0][0] = __builtin_amdgcn_mfma_f32_16x16x32_f16(a0, b0, acc[0][0], 0,0,0);
        acc[0][1] = __builtin_amdgcn_mfma_f32_16x16x32_f16(a0, b1, acc[0][1], 0,0,0);
        acc[1][0] = __builtin_amdgcn_mfma_f32_16x16x32_f16(a1, b0, acc[1][0], 0,0,0);
        acc[1][1] = __builtin_amdgcn_mfma_f32_16x16x32_f16(a1, b1, acc[1][1], 0,0,0);
    }
    int rloc = (lane >> 4)*4;      // C/D: col=lane&15, row=(lane>>4)*4+reg  [m89/m91]
#pragma unroll
    for (int sm = 0; sm < 2; sm++)
#pragma unroll
    for (int sn = 0; sn < 2; sn++) {
        f32x4 a = acc[sm][sn];
        int c  = bn + wn + sn*16 + lo4;
        int rb = bm + wm + sm*16 + rloc;
        if constexpr (MODE == 0) {
#pragma unroll
            for (int r = 0; r < 4; r++)
                if (rb + r < M) het[(rb + r)*E2_ + c] = a[r] + bcat[c];
        } else if constexpr (MODE == 1) {
            f16x4 o = {(f16)a[0], (f16)a[1], (f16)a[2], (f16)a[3]};
            *(f16x4*)(outp16 + (long long)bz*E2_*L_ + (long long)c*L_ + rb) = o;
        } else {
#pragma unroll
            for (int r = 0; r < 4; r++) {
                int row = rb + r;
                if (row < M) {
                    int i = row / NE_;
                    int j = row - i*NE_;
                    int sel = (c < H_) ? i : j;
                    float bias = het[(bz*NE_ + sel)*E2_ + c];
                    float v = tanhf(a[r] + bias);
                    long long o = (c < H_)
                        ? ((long long)((bz*NE_ + i)*NE_ + j))*H_ + c
                        : OUT_HALF + ((long long)((bz*NE_ + i)*NE_ + j))*H_ + (c - H_);
                    outp[o] = v;
                }
            }
        }
    }
}

extern "C" void kernel_launch(void* const* d_in, const int* in_sizes, int n_in,
                              void* d_out, int out_size, void* d_ws, size_t ws_size,
                              hipStream_t stream) {
    const float* seq  = (const float*)d_in[0];
    const float* attn = (const float*)d_in[1];
    const float* Wh   = (const float*)d_in[2];
    const float* bh   = (const float*)d_in[3];
    const float* Wt   = (const float*)d_in[4];
    const float* bt   = (const float*)d_in[5];
    const int* mpos   = (const int*)d_in[6];
    const int* mmask  = (const int*)d_in[7];
    float* out = (float*)d_out;
    char* ws = (char*)d_ws;
    // workspace layout (bytes, 256-aligned)
    f16*   ent   = (f16*)  (ws + 0);         //  168*768      f16
    f16*   wtop  = (f16*)  (ws + 258048);    // 1536*768      f16 [c][h]
    f16*   wbot  = (f16*)  (ws + 2617344);   // 1536*768      f16 [c][h]
    float* bcat  = (float*)(ws + 4976640);   // 1536          f32
    float* het   = (float*)(ws + 4982784);   //  168*1536     f32
    float* eatt  = (float*)(ws + 6014976);   // 4*42*12*1024  f32 (dead after k_ht)
    f16*   HT    = (f16*)  (ws + 14272512);  // 4*1792*1024   f16
    f16*   seqWT = (f16*)  (ws + 28952576);  // 4*1536*1024   f16 (transposed)
    f16*   seq16 = (f16*)  (ws + 6014976);   // 4*1024*768    f16 — reuses eatt region
    // total 41,535,488 B

    k_prep   <<<4608, 256, 0, stream>>>(Wh, bh, Wt, bt, wtop, wbot, bcat);
    k_ent_emb<<<dim3(NE_, B_), 256, 0, stream>>>(seq, mpos, mmask, ent);
    k_ent_att<<<dim3(NH_, NE_, B_), 256, 0, stream>>>(attn, mpos, mmask, eatt);
    k_ht     <<<dim3(NE_, NE_, B_), 256, 0, stream>>>(eatt, HT);
    k_seq16  <<<3072, 256, 0, stream>>>(seq, seq16);   // after k_ht: overwrites eatt
    // het[168,1536] = ent @ wtop^T + bcat
    k_gemm<0><<<dim3(3, 24, 1), 256, 0, stream>>>(ent, wtop, 168, 768, 0, 0,
        het, bcat, nullptr, nullptr);
    // seqWT[b][c][l] = (seq_b @ wbot^T)^T
    k_gemm<1><<<dim3(16, 24, B_), 256, 0, stream>>>(seq16, wbot, 1024, 768,
        (long long)L_*H_, 0, nullptr, nullptr, nullptr, seqWT);
    // out = tanh(HT_b @ seqWT_b^T + het-bias), split halves
    k_gemm<2><<<dim3(28, 24, B_), 256, 0, stream>>>(HT, seqWT, 1764, 1024,
        (long long)HTP_*L_, (long long)E2_*L_, het, nullptr, out, nullptr);
}

// Round 3
// 403.586 us; speedup vs baseline: 1.0648x; 1.0648x over previous
//
#include <hip/hip_runtime.h>
#include <math.h>

typedef _Float16 f16;
typedef __attribute__((ext_vector_type(4))) _Float16 f16x4;
typedef __attribute__((ext_vector_type(8))) _Float16 f16x8;
typedef __attribute__((ext_vector_type(4))) float f32x4;

#define B_    4
#define L_    1024
#define H_    768
#define NH_   12
#define NE_   42
#define M_    8
#define E2_   1536              // 2*H
#define HTP_  1792              // HT rows padded to 14*128
#define OUT_HALF 5419008LL      // B*NE*NE*H

// async global->LDS, 16B per lane. LDS dest is wave-uniform base + lane*16B.
typedef __attribute__((address_space(1))) const unsigned char ga_t;
typedef __attribute__((address_space(3))) unsigned char la_t;
__device__ __forceinline__ void async16(const void* g, void* l) {
    __builtin_amdgcn_global_load_lds((ga_t*)g, (la_t*)l, 16, 0, 0);
}

// ---------------- ent_emb: masked logsumexp over mentions -> f16 [168][768]
__global__ void k_ent_emb(const float* __restrict__ seq,
                          const int* __restrict__ mpos,
                          const int* __restrict__ mmask,
                          f16* __restrict__ ent) {
    int e = blockIdx.x, b = blockIdx.y;
    int tid = threadIdx.x;
    const int* mp = mpos  + (b*NE_ + e)*M_;
    const int* mk = mmask + (b*NE_ + e)*M_;
    int pos[M_], msk[M_];
#pragma unroll
    for (int m = 0; m < M_; m++) { msk[m] = mk[m]; pos[m] = mp[m] + 1; }
#pragma unroll
    for (int q = 0; q < 3; q++) {
        int h = tid + q*256;
        float mx = -1e30f, vals[M_];
#pragma unroll
        for (int m = 0; m < M_; m++) {
            vals[m] = 0.f;
            if (msk[m]) {
                float v = seq[((long long)b*L_ + pos[m])*H_ + h];
                vals[m] = v; mx = fmaxf(mx, v);
            }
        }
        float s = 0.f;
#pragma unroll
        for (int m = 0; m < M_; m++) if (msk[m]) s += expf(vals[m] - mx);
        float lse = (mx > -1e29f) ? mx + logf(s) : 0.f;
        ent[(b*NE_ + e)*H_ + h] = (f16)lse;
    }
}

// ---------------- ent_att: mean over valid mentions -> f16 [B][NE][NH][L]
__global__ void k_ent_att(const float* __restrict__ attn,
                          const int* __restrict__ mpos,
                          const int* __restrict__ mmask,
                          f16* __restrict__ eatt) {
    int nh = blockIdx.x, e = blockIdx.y, b = blockIdx.z;
    int tid = threadIdx.x;
    int l0 = tid * 4;
    const int* mp = mpos  + (b*NE_ + e)*M_;
    const int* mk = mmask + (b*NE_ + e)*M_;
    const float* abase = attn + (long long)(b*NH_ + nh) * L_ * L_;
    f32x4 acc = {0,0,0,0}; int cnt = 0;
#pragma unroll
    for (int m = 0; m < M_; m++) {
        if (mk[m]) {                       // wave-uniform branch
            cnt++;
            const float* row = abase + (long long)(mp[m] + 1) * L_;
            acc += *(const f32x4*)(row + l0);
        }
    }
    float inv = 1.f / (float)(cnt > 0 ? cnt : 1);
    f16x4 o = {(f16)(acc[0]*inv), (f16)(acc[1]*inv), (f16)(acc[2]*inv), (f16)(acc[3]*inv)};
    *(f16x4*)(eatt + ((long long)(b*NE_ + e)*NH_ + nh)*L_ + l0) = o;
}

// ---------------- ht: (1/NH) sum_h ea_i*ea_j, relu, L-normalize -> f16 HT [B][HTP][L]
// block = (b, i, jgroup of 7); ei cached in LDS (24KB)
__global__ __launch_bounds__(256) void k_ht(const f16* __restrict__ eatt,
                                            f16* __restrict__ HT) {
    int jg = blockIdx.x, i = blockIdx.y, b = blockIdx.z;
    int tid = threadIdx.x;
    __shared__ __align__(16) f16 ei_s[NH_*L_];   // 24KB
    __shared__ float red[4];
    const f16* ei = eatt + (long long)(b*NE_ + i)*NH_*L_;
#pragma unroll
    for (int q = 0; q < 6; q++) {
        int off = (q*256 + tid)*8;
        *(f16x8*)(ei_s + off) = *(const f16x8*)(ei + off);
    }
    __syncthreads();
    int l0 = tid*4;
    int wave = tid >> 6, lane = tid & 63;
    for (int jj = 0; jj < 7; jj++) {
        int j = jg*7 + jj;
        const f16* ej = eatt + (long long)(b*NE_ + j)*NH_*L_;
        f32x4 acc = {0,0,0,0};
#pragma unroll
        for (int h = 0; h < NH_; h++) {
            f16x4 vi = *(const f16x4*)(ei_s + h*L_ + l0);
            f16x4 vj = *(const f16x4*)(ej   + h*L_ + l0);
#pragma unroll
            for (int r = 0; r < 4; r++) acc[r] += (float)vi[r] * (float)vj[r];
        }
        float v[4]; float s = 0.f;
#pragma unroll
        for (int r = 0; r < 4; r++) {
            float t = acc[r] * (1.f/12.f);
            t = t > 0.f ? t : 0.f;
            v[r] = t; s += t;
        }
#pragma unroll
        for (int m = 1; m < 64; m <<= 1) s += __shfl_xor(s, m, 64);
        if (lane == 0) red[wave] = s;
        __syncthreads();
        float S = red[0] + red[1] + red[2] + red[3];
        __syncthreads();          // red reusable next iter
        float sc = 1.f / (S + 1e-10f);
        f16x4 o = {(f16)(v[0]*sc), (f16)(v[1]*sc), (f16)(v[2]*sc), (f16)(v[3]*sc)};
        *(f16x4*)(HT + ((long long)b*HTP_ + i*NE_ + j)*L_ + l0) = o;
    }
}

// ---------------- prep: 32x32 LDS tile transpose W[h][c] -> w*[c][h] (f16) + bias
__global__ __launch_bounds__(256)
void k_prep(const float* __restrict__ Wh, const float* __restrict__ Wt,
            const float* __restrict__ bh, const float* __restrict__ bt,
            f16* __restrict__ wtop, f16* __restrict__ wbot,
            float* __restrict__ bcat) {
    __shared__ float tile[32][33];
    int tx = blockIdx.x, ty = blockIdx.y, m = blockIdx.z;
    const float* src = (m & 1) ? Wt : Wh;
    int roff = (m & 2) ? H_ : 0;           // 0: top half rows, 1: bottom
    f16* dst = (m & 2) ? wbot : wtop;
    int coff = (m & 1) ? H_ : 0;
    int x = threadIdx.x & 31, y8 = threadIdx.x >> 5;
#pragma unroll
    for (int r = 0; r < 4; r++) {
        int h = ty*32 + y8 + r*8, c = tx*32 + x;
        tile[y8 + r*8][x] = src[(long long)(roff + h)*H_ + c];
    }
    __syncthreads();
#pragma unroll
    for (int r = 0; r < 4; r++) {
        int c2 = tx*32 + y8 + r*8, h2 = ty*32 + x;
        dst[(long long)(coff + c2)*H_ + h2] = (f16)tile[x][y8 + r*8];
    }
    if (tx == 0 && ty == 0 && m == 0) {
        for (int idx = threadIdx.x; idx < E2_; idx += 256)
            bcat[idx] = (idx < H_) ? bh[idx] : bt[idx - H_];
    }
}

// ---------------- seq f32 -> f16 copy
__global__ void k_seq16(const float* __restrict__ seq, f16* __restrict__ seq16) {
    int idx = (blockIdx.x*256 + threadIdx.x) * 4;
    f32x4 v = *(const f32x4*)(seq + idx);
    f16x4 o = {(f16)v[0], (f16)v[1], (f16)v[2], (f16)v[3]};
    *(f16x4*)(seq16 + idx) = o;
}

// ---------------- small MFMA GEMM 64x64 (het only): het = ent @ wtop^T + bcat
#define LDSS 40
__global__ __launch_bounds__(256)
void k_gemm_het(const f16* __restrict__ A, const f16* __restrict__ BT,
                int M, int K, float* __restrict__ het, const float* __restrict__ bcat) {
    __shared__ __align__(16) f16 As[64*LDSS];
    __shared__ __align__(16) f16 Bs[64*LDSS];
    int bm = blockIdx.x*64, bn = blockIdx.y*64;
    int tid = threadIdx.x;
    int wave = tid >> 6, lane = tid & 63;
    int wm = (wave >> 1)*32, wn = (wave & 1)*32;
    int lo4 = lane & 15, kq = (lane >> 4)*8;
    int srow = tid >> 2, scol = (tid & 3)*8;
    bool aval = (bm + srow) < M;
    const f16* aptr = A + (long long)(bm + srow)*K + scol;
    const f16* bptr = BT + (long long)(bn + srow)*K + scol;
    f32x4 acc[2][2] = {};
    for (int k0 = 0; k0 < K; k0 += 32) {
        uint4 zero = {0,0,0,0};
        uint4 av = aval ? *(const uint4*)(aptr + k0) : zero;
        uint4 bv = *(const uint4*)(bptr + k0);
        __syncthreads();
        *(uint4*)(As + srow*LDSS + scol) = av;
        *(uint4*)(Bs + srow*LDSS + scol) = bv;
        __syncthreads();
        f16x8 a0 = *(const f16x8*)(As + (wm +      lo4)*LDSS + kq);
        f16x8 a1 = *(const f16x8*)(As + (wm + 16 + lo4)*LDSS + kq);
        f16x8 b0 = *(const f16x8*)(Bs + (wn +      lo4)*LDSS + kq);
        f16x8 b1 = *(const f16x8*)(Bs + (wn + 16 + lo4)*LDSS + kq);
        acc[0][0] = __builtin_amdgcn_mfma_f32_16x16x32_f16(a0, b0, acc[0][0], 0,0,0);
        acc[0][1] = __builtin_amdgcn_mfma_f32_16x16x32_f16(a0, b1, acc[0][1], 0,0,0);
        acc[1][0] = __builtin_amdgcn_mfma_f32_16x16x32_f16(a1, b0, acc[1][0], 0,0,0);
        acc[1][1] = __builtin_amdgcn_mfma_f32_16x16x32_f16(a1, b1, acc[1][1], 0,0,0);
    }
    int rloc = (lane >> 4)*4;      // C/D: col=lane&15, row=(lane>>4)*4+reg
#pragma unroll
    for (int sm = 0; sm < 2; sm++)
#pragma unroll
    for (int sn = 0; sn < 2; sn++) {
        f32x4 a = acc[sm][sn];
        int c  = bn + wn + sn*16 + lo4;
        int rb = bm + wm + sm*16 + rloc;
#pragma unroll
        for (int r = 0; r < 4; r++)
            if (rb + r < M) het[(rb + r)*E2_ + c] = a[r] + bcat[c];
    }
}

// ---------------- MFMA f16 GEMM, 128x128 tile, BK=32, global_load_lds staging
// A [M][K] row-major, BT [N][K] row-major (i.e. C = A @ BT^T). K mult of 32.
// MODE 1: store C transposed as f16 -> outp16[bz][c][l]
// MODE 2: tanh(C + het bias), split-write f32 halves of d_out
template<int MODE>
__global__ __launch_bounds__(256)
void k_gemm2(const f16* __restrict__ A, const f16* __restrict__ BT, int K,
             long long strideA, long long strideBT,
             const float* __restrict__ het, float* __restrict__ outp,
             f16* __restrict__ outp16) {
    __shared__ __align__(16) f16 As[128*32];   // 8KB, unpadded (global_load_lds)
    __shared__ __align__(16) f16 Bs[128*32];
    int bm = blockIdx.x*128, bn = blockIdx.y*128, bz = blockIdx.z;
    const f16* Ab = A + strideA*bz;
    const f16* Bb = BT + strideBT*bz;
    int tid = threadIdx.x, wave = tid >> 6, lane = tid & 63;
    int wm = (wave >> 1)*64, wn = (wave & 1)*64;
    int lo4 = lane & 15, kq = (lane >> 4)*8;
    // staging: wave w covers rows [w*32, w*32+32); two 16-row calls each for A,B
    int lrow = lane >> 2, lcol = (lane & 3)*8;
    const f16* ag = Ab + (long long)(bm + wave*32 + lrow)*K + lcol;
    const f16* bg = Bb + (long long)(bn + wave*32 + lrow)*K + lcol;
    f16* asl = As + wave*1024;   // 16 rows * 32 elems * 2 calls
    f16* bsl = Bs + wave*1024;
    f32x4 acc[4][4] = {};
    for (int k0 = 0; k0 < K; k0 += 32) {
        async16(ag + k0,          asl);
        async16(ag + k0 + 16*K,   asl + 512);
        async16(bg + k0,          bsl);
        async16(bg + k0 + 16*K,   bsl + 512);
        __syncthreads();
        f16x8 af[4], bf[4];
#pragma unroll
        for (int s = 0; s < 4; s++) {
            af[s] = *(const f16x8*)(As + (wm + s*16 + lo4)*32 + kq);
            bf[s] = *(const f16x8*)(Bs + (wn + s*16 + lo4)*32 + kq);
        }
#pragma unroll
        for (int sm = 0; sm < 4; sm++)
#pragma unroll
        for (int sn = 0; sn < 4; sn++)
            acc[sm][sn] = __builtin_amdgcn_mfma_f32_16x16x32_f16(af[sm], bf[sn], acc[sm][sn], 0,0,0);
        __syncthreads();
    }
    int rloc = (lane >> 4)*4;
#pragma unroll
    for (int sm = 0; sm < 4; sm++)
#pragma unroll
    for (int sn = 0; sn < 4; sn++) {
        f32x4 a = acc[sm][sn];
        int c  = bn + wn + sn*16 + lo4;
        int rb = bm + wm + sm*16 + rloc;
        if constexpr (MODE == 1) {
            f16x4 o = {(f16)a[0], (f16)a[1], (f16)a[2], (f16)a[3]};
            *(f16x4*)(outp16 + (long long)bz*E2_*L_ + (long long)c*L_ + rb) = o;
        } else {
#pragma unroll
            for (int r = 0; r < 4; r++) {
                int row = rb + r;
                if (row < NE_*NE_) {
                    int i = row / NE_;
                    int j = row - i*NE_;
                    int sel = (c < H_) ? i : j;
                    float bias = het[(bz*NE_ + sel)*E2_ + c];
                    float v = tanhf(a[r] + bias);
                    long long o = (c < H_)
                        ? ((long long)((bz*NE_ + i)*NE_ + j))*H_ + c
                        : OUT_HALF + ((long long)((bz*NE_ + i)*NE_ + j))*H_ + (c - H_);
                    outp[o] = v;
                }
            }
        }
    }
}

extern "C" void kernel_launch(void* const* d_in, const int* in_sizes, int n_in,
                              void* d_out, int out_size, void* d_ws, size_t ws_size,
                              hipStream_t stream) {
    const float* seq  = (const float*)d_in[0];
    const float* attn = (const float*)d_in[1];
    const float* Wh   = (const float*)d_in[2];
    const float* bh   = (const float*)d_in[3];
    const float* Wt   = (const float*)d_in[4];
    const float* bt   = (const float*)d_in[5];
    const int* mpos   = (const int*)d_in[6];
    const int* mmask  = (const int*)d_in[7];
    float* out = (float*)d_out;
    char* ws = (char*)d_ws;
    // workspace layout (bytes, 16-aligned)
    f16*   ent   = (f16*)  (ws + 0);         //  168*768          f16
    f16*   wtop  = (f16*)  (ws + 258048);    // 1536*768          f16 [c][h]
    f16*   wbot  = (f16*)  (ws + 2617344);   // 1536*768          f16 [c][h]
    float* bcat  = (float*)(ws + 4976640);   // 1536              f32
    float* het   = (float*)(ws + 4982784);   //  168*1536         f32
    f16*   eatt  = (f16*)  (ws + 6014976);   // 4*42*12*1024      f16
    f16*   seq16 = (f16*)  (ws + 10143744);  // 4*1024*768        f16
    f16*   HT    = (f16*)  (ws + 16435200);  // 4*1792*1024       f16
    f16*   seqWT = (f16*)  (ws + 31115264);  // 4*1536*1024       f16 (transposed)
    // total 43,698,176 B

    k_prep   <<<dim3(24, 24, 4), 256, 0, stream>>>(Wh, Wt, bh, bt, wtop, wbot, bcat);
    k_ent_emb<<<dim3(NE_, B_), 256, 0, stream>>>(seq, mpos, mmask, ent);
    k_ent_att<<<dim3(NH_, NE_, B_), 256, 0, stream>>>(attn, mpos, mmask, eatt);
    k_ht     <<<dim3(6, NE_, B_), 256, 0, stream>>>(eatt, HT);
    k_seq16  <<<3072, 256, 0, stream>>>(seq, seq16);
    // het[168,1536] = ent @ wtop^T + bcat
    k_gemm_het<<<dim3(3, 24, 1), 256, 0, stream>>>(ent, wtop, 168, 768, het, bcat);
    // seqWT[b][c][l] = (seq_b @ wbot^T)^T
    k_gemm2<1><<<dim3(8, 12, B_), 256, 0, stream>>>(seq16, wbot, 768,
        (long long)L_*H_, 0, nullptr, nullptr, seqWT);
    // out = tanh(HT_b @ seqWT_b^T + het-bias), split halves
    k_gemm2<2><<<dim3(14, 12, B_), 256, 0, stream>>>(HT, seqWT, 1024,
        (long long)HTP_*L_, (long long)E2_*L_, het, out, nullptr);
}

// Round 4
// 365.114 us; speedup vs baseline: 1.1770x; 1.1054x over previous
//
#include <hip/hip_runtime.h>
#include <math.h>

typedef _Float16 f16;
typedef __attribute__((ext_vector_type(4))) _Float16 f16x4;
typedef __attribute__((ext_vector_type(8))) _Float16 f16x8;
typedef __attribute__((ext_vector_type(4))) float f32x4;

#define B_    4
#define L_    1024
#define H_    768
#define NH_   12
#define NE_   42
#define M_    8
#define E2_   1536              // 2*H
#define HTP_  1792              // HT rows padded to 14*128
#define OUT_HALF 5419008LL      // B*NE*NE*H

// async global->LDS, 16B per lane. LDS dest is wave-uniform base + lane*16B.
typedef __attribute__((address_space(1))) const unsigned char ga_t;
typedef __attribute__((address_space(3))) unsigned char la_t;
__device__ __forceinline__ void async16(const void* g, void* l) {
    __builtin_amdgcn_global_load_lds((ga_t*)g, (la_t*)l, 16, 0, 0);
}

// ===================== device bodies =====================

// ---- prep: 32x32 LDS tile transpose W[h][c] -> w*[c][h] (f16) + bias concat
__device__ void prep_body(int bid, char* smem,
                          const float* __restrict__ Wh, const float* __restrict__ Wt,
                          const float* __restrict__ bh, const float* __restrict__ bt,
                          f16* __restrict__ wtop, f16* __restrict__ wbot,
                          float* __restrict__ bcat) {
    float (*tile)[33] = (float(*)[33])smem;           // 32*33*4 = 4224 B
    int tx = bid % 24, ty = (bid / 24) % 24, m = bid / 576;
    const float* src = (m & 1) ? Wt : Wh;
    int roff = (m & 2) ? H_ : 0;
    f16* dst = (m & 2) ? wbot : wtop;
    int coff = (m & 1) ? H_ : 0;
    int x = threadIdx.x & 31, y8 = threadIdx.x >> 5;
#pragma unroll
    for (int r = 0; r < 4; r++) {
        int h = ty*32 + y8 + r*8, c = tx*32 + x;
        tile[y8 + r*8][x] = src[(long long)(roff + h)*H_ + c];
    }
    __syncthreads();
#pragma unroll
    for (int r = 0; r < 4; r++) {
        int c2 = tx*32 + y8 + r*8, h2 = ty*32 + x;
        dst[(long long)(coff + c2)*H_ + h2] = (f16)tile[x][y8 + r*8];
    }
    if (bid == 0) {
        for (int idx = threadIdx.x; idx < E2_; idx += 256)
            bcat[idx] = (idx < H_) ? bh[idx] : bt[idx - H_];
    }
}

// ---- seq f32 -> f16
__device__ void seq16_body(int bid, const float* __restrict__ seq,
                           f16* __restrict__ seq16) {
    int idx = (bid*256 + threadIdx.x) * 4;
    f32x4 v = *(const f32x4*)(seq + idx);
    f16x4 o = {(f16)v[0], (f16)v[1], (f16)v[2], (f16)v[3]};
    *(f16x4*)(seq16 + idx) = o;
}

// ---- ent_emb: masked logsumexp over mentions -> f16 [168][768]
__device__ void ent_emb_body(int bid, const float* __restrict__ seq,
                             const int* __restrict__ mpos,
                             const int* __restrict__ mmask,
                             f16* __restrict__ ent) {
    int e = bid % NE_, b = bid / NE_;
    int tid = threadIdx.x;
    const int* mp = mpos  + (b*NE_ + e)*M_;
    const int* mk = mmask + (b*NE_ + e)*M_;
    int pos[M_], msk[M_];
#pragma unroll
    for (int m = 0; m < M_; m++) { msk[m] = mk[m]; pos[m] = mp[m] + 1; }
#pragma unroll
    for (int q = 0; q < 3; q++) {
        int h = tid + q*256;
        float mx = -1e30f, vals[M_];
#pragma unroll
        for (int m = 0; m < M_; m++) {
            vals[m] = 0.f;
            if (msk[m]) {
                float v = seq[((long long)b*L_ + pos[m])*H_ + h];
                vals[m] = v; mx = fmaxf(mx, v);
            }
        }
        float s = 0.f;
#pragma unroll
        for (int m = 0; m < M_; m++) if (msk[m]) s += expf(vals[m] - mx);
        float lse = (mx > -1e29f) ? mx + logf(s) : 0.f;
        ent[(b*NE_ + e)*H_ + h] = (f16)lse;
    }
}

// ---- ent_att: mean over valid mentions -> f16 [B][NE][NH][L]
__device__ void ent_att_body(int bid, const float* __restrict__ attn,
                             const int* __restrict__ mpos,
                             const int* __restrict__ mmask,
                             f16* __restrict__ eatt) {
    int nh = bid % NH_, e = (bid / NH_) % NE_, b = bid / (NH_*NE_);
    int tid = threadIdx.x;
    int l0 = tid * 4;
    const int* mp = mpos  + (b*NE_ + e)*M_;
    const int* mk = mmask + (b*NE_ + e)*M_;
    const float* abase = attn + (long long)(b*NH_ + nh) * L_ * L_;
    f32x4 acc = {0,0,0,0}; int cnt = 0;
#pragma unroll
    for (int m = 0; m < M_; m++) {
        if (mk[m]) {                       // wave-uniform branch
            cnt++;
            const float* row = abase + (long long)(mp[m] + 1) * L_;
            acc += *(const f32x4*)(row + l0);
        }
    }
    float inv = 1.f / (float)(cnt > 0 ? cnt : 1);
    f16x4 o = {(f16)(acc[0]*inv), (f16)(acc[1]*inv), (f16)(acc[2]*inv), (f16)(acc[3]*inv)};
    *(f16x4*)(eatt + ((long long)(b*NE_ + e)*NH_ + nh)*L_ + l0) = o;
}

// ---- ht: (1/NH) sum_h ea_i*ea_j, relu, L-normalize -> f16 HT [B][HTP][L]
__device__ void ht_body(int bid, char* smem, const f16* __restrict__ eatt,
                        f16* __restrict__ HT) {
    int jg = bid % 6, i = (bid / 6) % NE_, b = bid / 252;
    int tid = threadIdx.x;
    f16* ei_s = (f16*)smem;                       // 24576 B
    float* red = (float*)(smem + NH_*L_*2);       // +16 B
    const f16* ei = eatt + (long long)(b*NE_ + i)*NH_*L_;
#pragma unroll
    for (int q = 0; q < 6; q++) {
        int off = (q*256 + tid)*8;
        *(f16x8*)(ei_s + off) = *(const f16x8*)(ei + off);
    }
    __syncthreads();
    int l0 = tid*4;
    int wave = tid >> 6, lane = tid & 63;
    for (int jj = 0; jj < 7; jj++) {
        int j = jg*7 + jj;
        const f16* ej = eatt + (long long)(b*NE_ + j)*NH_*L_;
        f32x4 acc = {0,0,0,0};
#pragma unroll
        for (int h = 0; h < NH_; h++) {
            f16x4 vi = *(const f16x4*)(ei_s + h*L_ + l0);
            f16x4 vj = *(const f16x4*)(ej   + h*L_ + l0);
#pragma unroll
            for (int r = 0; r < 4; r++) acc[r] += (float)vi[r] * (float)vj[r];
        }
        float v[4]; float s = 0.f;
#pragma unroll
        for (int r = 0; r < 4; r++) {
            float t = acc[r] * (1.f/12.f);
            t = t > 0.f ? t : 0.f;
            v[r] = t; s += t;
        }
#pragma unroll
        for (int m = 1; m < 64; m <<= 1) s += __shfl_xor(s, m, 64);
        if (lane == 0) red[wave] = s;
        __syncthreads();
        float S = red[0] + red[1] + red[2] + red[3];
        __syncthreads();
        float sc = 1.f / (S + 1e-10f);
        f16x4 o = {(f16)(v[0]*sc), (f16)(v[1]*sc), (f16)(v[2]*sc), (f16)(v[3]*sc)};
        *(f16x4*)(HT + ((long long)b*HTP_ + i*NE_ + j)*L_ + l0) = o;
    }
}

// ---- small MFMA GEMM 64x64: het = ent @ wtop^T + bcat
#define LDSS 40
__device__ void gemm_het_body(int bx, int by, char* smem,
                              const f16* __restrict__ A, const f16* __restrict__ BT,
                              float* __restrict__ het, const float* __restrict__ bcat) {
    const int M = 168, K = 768;
    f16* As = (f16*)smem;                 // 64*40*2 = 5120 B
    f16* Bs = (f16*)(smem + 64*LDSS*2);   // 5120 B
    int bm = bx*64, bn = by*64;
    int tid = threadIdx.x;
    int wave = tid >> 6, lane = tid & 63;
    int wm = (wave >> 1)*32, wn = (wave & 1)*32;
    int lo4 = lane & 15, kq = (lane >> 4)*8;
    int srow = tid >> 2, scol = (tid & 3)*8;
    bool aval = (bm + srow) < M;
    const f16* aptr = A + (long long)(bm + srow)*K + scol;
    const f16* bptr = BT + (long long)(bn + srow)*K + scol;
    f32x4 acc[2][2] = {};
    for (int k0 = 0; k0 < K; k0 += 32) {
        uint4 zero = {0,0,0,0};
        uint4 av = aval ? *(const uint4*)(aptr + k0) : zero;
        uint4 bv = *(const uint4*)(bptr + k0);
        __syncthreads();
        *(uint4*)(As + srow*LDSS + scol) = av;
        *(uint4*)(Bs + srow*LDSS + scol) = bv;
        __syncthreads();
        f16x8 a0 = *(const f16x8*)(As + (wm +      lo4)*LDSS + kq);
        f16x8 a1 = *(const f16x8*)(As + (wm + 16 + lo4)*LDSS + kq);
        f16x8 b0 = *(const f16x8*)(Bs + (wn +      lo4)*LDSS + kq);
        f16x8 b1 = *(const f16x8*)(Bs + (wn + 16 + lo4)*LDSS + kq);
        acc[0][0] = __builtin_amdgcn_mfma_f32_16x16x32_f16(a0, b0, acc[0][0], 0,0,0);
        acc[0][1] = __builtin_amdgcn_mfma_f32_16x16x32_f16(a0, b1, acc[0][1], 0,0,0);
        acc[1][0] = __builtin_amdgcn_mfma_f32_16x16x32_f16(a1, b0, acc[1][0], 0,0,0);
        acc[1][1] = __builtin_amdgcn_mfma_f32_16x16x32_f16(a1, b1, acc[1][1], 0,0,0);
    }
    int rloc = (lane >> 4)*4;      // C/D: col=lane&15, row=(lane>>4)*4+reg
#pragma unroll
    for (int sm = 0; sm < 2; sm++)
#pragma unroll
    for (int sn = 0; sn < 2; sn++) {
        f32x4 a = acc[sm][sn];
        int c  = bn + wn + sn*16 + lo4;
        int rb = bm + wm + sm*16 + rloc;
#pragma unroll
        for (int r = 0; r < 4; r++)
            if (rb + r < M) het[(rb + r)*E2_ + c] = a[r] + bcat[c];
    }
}

// ---- MFMA f16 GEMM 128x128, BK=32, global_load_lds staging.
// MODE 1: store C transposed f16 -> outp16[bz][c][l];  MODE 2: tanh + split f32 out
template<int MODE>
__device__ void gemm2_body(int bx, int by, int bz, char* smem,
                           const f16* __restrict__ A, const f16* __restrict__ BT, int K,
                           long long strideA, long long strideBT,
                           const float* __restrict__ het, float* __restrict__ outp,
                           f16* __restrict__ outp16) {
    f16* As = (f16*)smem;            // 8 KB, unpadded (global_load_lds)
    f16* Bs = (f16*)(smem + 8192);   // 8 KB
    int bm = bx*128, bn = by*128;
    const f16* Ab = A + strideA*bz;
    const f16* Bb = BT + strideBT*bz;
    int tid = threadIdx.x, wave = tid >> 6, lane = tid & 63;
    int wm = (wave >> 1)*64, wn = (wave & 1)*64;
    int lo4 = lane & 15, kq = (lane >> 4)*8;
    int lrow = lane >> 2, lcol = (lane & 3)*8;
    const f16* ag = Ab + (long long)(bm + wave*32 + lrow)*K + lcol;
    const f16* bg = Bb + (long long)(bn + wave*32 + lrow)*K + lcol;
    f16* asl = As + wave*1024;
    f16* bsl = Bs + wave*1024;
    f32x4 acc[4][4] = {};
    for (int k0 = 0; k0 < K; k0 += 32) {
        async16(ag + k0,          asl);
        async16(ag + k0 + 16*K,   asl + 512);
        async16(bg + k0,          bsl);
        async16(bg + k0 + 16*K,   bsl + 512);
        __syncthreads();
        f16x8 af[4], bf[4];
#pragma unroll
        for (int s = 0; s < 4; s++) {
            af[s] = *(const f16x8*)(As + (wm + s*16 + lo4)*32 + kq);
            bf[s] = *(const f16x8*)(Bs + (wn + s*16 + lo4)*32 + kq);
        }
#pragma unroll
        for (int sm = 0; sm < 4; sm++)
#pragma unroll
        for (int sn = 0; sn < 4; sn++)
            acc[sm][sn] = __builtin_amdgcn_mfma_f32_16x16x32_f16(af[sm], bf[sn], acc[sm][sn], 0,0,0);
        __syncthreads();
    }
    int rloc = (lane >> 4)*4;
#pragma unroll
    for (int sm = 0; sm < 4; sm++)
#pragma unroll
    for (int sn = 0; sn < 4; sn++) {
        f32x4 a = acc[sm][sn];
        int c  = bn + wn + sn*16 + lo4;
        int rb = bm + wm + sm*16 + rloc;
        if constexpr (MODE == 1) {
            f16x4 o = {(f16)a[0], (f16)a[1], (f16)a[2], (f16)a[3]};
            *(f16x4*)(outp16 + (long long)bz*E2_*L_ + (long long)c*L_ + rb) = o;
        } else {
#pragma unroll
            for (int r = 0; r < 4; r++) {
                int row = rb + r;
                if (row < NE_*NE_) {
                    int i = row / NE_;
                    int j = row - i*NE_;
                    int sel = (c < H_) ? i : j;
                    float bias = het[(bz*NE_ + sel)*E2_ + c];
                    float v = tanhf(a[r] + bias);
                    long long o = (c < H_)
                        ? ((long long)((bz*NE_ + i)*NE_ + j))*H_ + c
                        : OUT_HALF + ((long long)((bz*NE_ + i)*NE_ + j))*H_ + (c - H_);
                    outp[o] = v;
                }
            }
        }
    }
}

// ===================== fused launches =====================
// L1: prep (2304) | seq16 (3072) | ent_emb (168) | ent_att (2016)  = 7560 blocks
__global__ __launch_bounds__(256) void k_L1(
        const float* __restrict__ seq, const float* __restrict__ attn,
        const float* __restrict__ Wh, const float* __restrict__ bh,
        const float* __restrict__ Wt, const float* __restrict__ bt,
        const int* __restrict__ mpos, const int* __restrict__ mmask,
        f16* __restrict__ wtop, f16* __restrict__ wbot, float* __restrict__ bcat,
        f16* __restrict__ seq16, f16* __restrict__ ent, f16* __restrict__ eatt) {
    __shared__ __align__(16) char smem[4224];
    int bid = blockIdx.x;
    if (bid < 2304)       prep_body(bid, smem, Wh, Wt, bh, bt, wtop, wbot, bcat);
    else if (bid < 5376)  seq16_body(bid - 2304, seq, seq16);
    else if (bid < 5544)  ent_emb_body(bid - 5376, seq, mpos, mmask, ent);
    else                  ent_att_body(bid - 5544, attn, mpos, mmask, eatt);
}

// L2: gemm2<1> (384) | ht (1008) | gemm_het (72) = 1464 blocks
__global__ __launch_bounds__(256) void k_L2(
        const f16* __restrict__ seq16, const f16* __restrict__ wbot,
        const f16* __restrict__ ent, const f16* __restrict__ wtop,
        const float* __restrict__ bcat, const f16* __restrict__ eatt,
        f16* __restrict__ seqWT, float* __restrict__ het, f16* __restrict__ HT) {
    __shared__ __align__(16) char smem[24640];
    int bid = blockIdx.x;
    if (bid < 384) {
        int bx = bid & 7, by = (bid >> 3) % 12, bz = bid / 96;
        gemm2_body<1>(bx, by, bz, smem, seq16, wbot, 768,
                      (long long)L_*H_, 0, nullptr, nullptr, seqWT);
    } else if (bid < 1392) {
        ht_body(bid - 384, smem, eatt, HT);
    } else {
        int r = bid - 1392;
        gemm_het_body(r % 3, r / 3, smem, ent, wtop, het, bcat);
    }
}

// L3: gemm2<2>, grid (14,12,4)
__global__ __launch_bounds__(256) void k_L3(
        const f16* __restrict__ HT, const f16* __restrict__ seqWT,
        const float* __restrict__ het, float* __restrict__ outp) {
    __shared__ __align__(16) char smem[16384];
    gemm2_body<2>(blockIdx.x, blockIdx.y, blockIdx.z, smem, HT, seqWT, 1024,
                  (long long)HTP_*L_, (long long)E2_*L_, het, outp, nullptr);
}

extern "C" void kernel_launch(void* const* d_in, const int* in_sizes, int n_in,
                              void* d_out, int out_size, void* d_ws, size_t ws_size,
                              hipStream_t stream) {
    const float* seq  = (const float*)d_in[0];
    const float* attn = (const float*)d_in[1];
    const float* Wh   = (const float*)d_in[2];
    const float* bh   = (const float*)d_in[3];
    const float* Wt   = (const float*)d_in[4];
    const float* bt   = (const float*)d_in[5];
    const int* mpos   = (const int*)d_in[6];
    const int* mmask  = (const int*)d_in[7];
    float* out = (float*)d_out;
    char* ws = (char*)d_ws;
    f16*   ent   = (f16*)  (ws + 0);         //  168*768          f16
    f16*   wtop  = (f16*)  (ws + 258048);    // 1536*768          f16 [c][h]
    f16*   wbot  = (f16*)  (ws + 2617344);   // 1536*768          f16 [c][h]
    float* bcat  = (float*)(ws + 4976640);   // 1536              f32
    float* het   = (float*)(ws + 4982784);   //  168*1536         f32
    f16*   eatt  = (f16*)  (ws + 6014976);   // 4*42*12*1024      f16
    f16*   seq16 = (f16*)  (ws + 10143744);  // 4*1024*768        f16
    f16*   HT    = (f16*)  (ws + 16435200);  // 4*1792*1024       f16
    f16*   seqWT = (f16*)  (ws + 31115264);  // 4*1536*1024       f16 (transposed)
    // total 43,698,176 B

    k_L1<<<7560, 256, 0, stream>>>(seq, attn, Wh, bh, Wt, bt, mpos, mmask,
                                   wtop, wbot, bcat, seq16, ent, eatt);
    k_L2<<<1464, 256, 0, stream>>>(seq16, wbot, ent, wtop, bcat, eatt,
                                   seqWT, het, HT);
    k_L3<<<dim3(14, 12, B_), 256, 0, stream>>>(HT, seqWT, het, out);
}